// Round 11
// baseline (53.736 us; speedup 1.0000x reference)
//
#include <hip/hip_runtime.h>
#include <hip/hip_bf16.h>
#include <cstdint>

// ExemplarAttention: logits[b,c] = gamma * log( sum_{n: label[n]=c} exp(-beta * d[b,n]) + eps )
// d[b,n] = x2w[b] + e2w[n] - 2 * sum_k (x[b,k]*w[k]) * E[n,k]
//
// Round 11 (from r10 PMC postmortem: VALUBusy 30% = 64x-redundant X cvt; 1 block/CU):
//  - prep_x kernel: softmax(w) -> wbuf, X*w -> bf16 xbf, x2w. 3MB, ~1.5us. Kills the
//    64x-redundant in-gemm X conversion.
//  - gemm: 512 blocks x 512 thr (8 waves, 4Ex2B, wave 64x64), tile 256Ex128B, BK=32,
//    dbuf 48KB -> 2 independent blocks/CU (cross-block barrier-drain hiding).
//    X staged via global_load_lds (DMA, pre-swizzled source); E reg-staged f32->bf16
//    with fused e2w accumulation (4..8x redundancy OK). Both-sides (row>>1)&3 swizzle
//    (r10-validated: conflicts 1.67M->131K). One-hot-MFMA class reduce; no atomics.

typedef __attribute__((ext_vector_type(4))) float f32x4;
typedef __attribute__((ext_vector_type(8))) __bf16 bf16x8;
typedef __attribute__((ext_vector_type(4))) _Float16 half4;
typedef __attribute__((ext_vector_type(4))) unsigned int u32x4;

#define DDIM 512
#define NC 10
#define NCP 16
#define NECH 64    // exemplar chunks (16384/256)
#define EPSF 1e-9f

typedef const __attribute__((address_space(1))) void* gas_ptr;
typedef __attribute__((address_space(3))) void* las_ptr;

__device__ inline void async16(const void* g, void* l) {
  __builtin_amdgcn_global_load_lds((gas_ptr)g, (las_ptr)l, 16, 0, 0);
}

__device__ inline float softplus(float x) {
  return (x > 20.0f) ? x : log1pf(__expf(x));
}

// pack 2 f32 -> 2 bf16 (RNE), lo -> bits[15:0]
__device__ inline unsigned cvtpk(float lo, float hi) {
  unsigned r;
  asm("v_cvt_pk_bf16_f32 %0, %1, %2" : "=v"(r) : "v"(lo), "v"(hi));
  return r;
}

// ---- kernel 1: softmax(w) -> wbuf; X -> bf16(x*w) + x2w ---------------------
// 128 blocks x 512 threads; one row per wave (8 rows/block).
__global__ __launch_bounds__(512) void prep_x(
    const float* __restrict__ x, const float* __restrict__ wu,
    float* __restrict__ wbuf, unsigned short* __restrict__ xbf,
    float* __restrict__ x2w) {
  __shared__ float sm[16];
  const int tid = threadIdx.x, lane = tid & 63, wid = tid >> 6;

  float v = wu[tid];
  float m = v;
  #pragma unroll
  for (int o = 32; o > 0; o >>= 1) m = fmaxf(m, __shfl_xor(m, o, 64));
  if (lane == 0) sm[wid] = m;
  __syncthreads();
  float mm = sm[0];
  #pragma unroll
  for (int i = 1; i < 8; ++i) mm = fmaxf(mm, sm[i]);
  float e = __expf(v - mm);
  float s = e;
  #pragma unroll
  for (int o = 32; o > 0; o >>= 1) s += __shfl_xor(s, o, 64);
  if (lane == 0) sm[8 + wid] = s;
  __syncthreads();
  float ss = 0.f;
  #pragma unroll
  for (int i = 0; i < 8; ++i) ss += sm[8 + i];
  const float wv = e / ss + EPSF;
  wbuf[tid] = wv;   // all blocks write identical values (deterministic)

  // broadcast w slice for this lane's 8 columns via LDS
  __shared__ float wlds[512];
  wlds[tid] = wv;
  __syncthreads();
  const float4 wa = *(const float4*)&wlds[lane * 8];
  const float4 wb = *(const float4*)&wlds[lane * 8 + 4];

  const size_t row = (size_t)blockIdx.x * 8 + wid;
  const float* p = x + row * DDIM + lane * 8;
  float4 va = *(const float4*)(p);
  float4 vb = *(const float4*)(p + 4);
  float a0 = va.x * wa.x, a1 = va.y * wa.y, a2 = va.z * wa.z, a3 = va.w * wa.w;
  float a4 = vb.x * wb.x, a5 = vb.y * wb.y, a6 = vb.z * wb.z, a7 = vb.w * wb.w;
  float s2 = a0 * va.x + a1 * va.y + a2 * va.z + a3 * va.w
           + a4 * vb.x + a5 * vb.y + a6 * vb.z + a7 * vb.w;
  u32x4 pk;
  pk[0] = cvtpk(a0, a1); pk[1] = cvtpk(a2, a3);
  pk[2] = cvtpk(a4, a5); pk[3] = cvtpk(a6, a7);
  *(u32x4*)(xbf + row * DDIM + lane * 8) = pk;
  #pragma unroll
  for (int o = 32; o > 0; o >>= 1) s2 += __shfl_xor(s2, o, 64);
  if (lane == 0) x2w[row] = s2;
}

// ---- kernel 2: fused GEMM + exp + class partial reduce ----------------------
// grid: 512 blocks (64 e-tiles x 8 b-tiles), 512 threads = 8 waves (4E x 2B),
// wave tile 64x64. Tile 256E x 128B, BK=32, dbuf 2 x (E 16KB | X 8KB) = 48KB.
// LDS chunk q (16B): row = q>>2, c = q&3, global kchunk = c ^ ((row>>1)&3).
// E reg-staged (f32->cvt->linear ds_write); X via global_load_lds (linear dest,
// pre-swizzled source). Readers: byte = row*64 + ((ch ^ ((row>>1)&3))*16).
__global__ __launch_bounds__(512, 4) void gemm_mega(
    const float* __restrict__ ex, const unsigned short* __restrict__ xbf,
    const int* __restrict__ labels, const float* __restrict__ wbuf,
    const float* __restrict__ x2w, const float* __restrict__ bu,
    float* __restrict__ part) {
  __shared__ __attribute__((aligned(16))) unsigned short smem[2 * 12288];  // 48KB dbuf
  __shared__ float wlds[512];
  __shared__ float e2l[256];
  __shared__ int lab[256];
  const int tid = threadIdx.x, lane = tid & 63, wid = tid >> 6;

  // XCD-aware bijective swizzle: XCD x owns e-tiles [x*8, x*8+8) x 8 b-tiles.
  const int orig = blockIdx.x;             // 0..511
  const int xcd = orig & 7;
  const int local = orig >> 3;             // 0..63
  const int be = xcd * 8 + (local >> 3);   // exemplar tile 0..63
  const int bb = local & 7;                // batch tile 0..7

  if (tid < 256) lab[tid] = labels[be * 256 + tid];
  wlds[tid] = wbuf[tid];

  // ---- E staging geometry (reg-staged, 2 chunks/thread, same row) ----
  const int erow = tid >> 1;                          // 0..255
  const int c0 = (tid & 1) * 2;                       // 0 or 2
  const int kc0 = c0 ^ ((erow >> 1) & 3);
  const int kc1 = (c0 + 1) ^ ((erow >> 1) & 3);
  const float* eP0 = ex + (size_t)(be * 256 + erow) * DDIM + kc0 * 8;
  const float* eP1 = ex + (size_t)(be * 256 + erow) * DDIM + kc1 * 8;
  const int dE0 = tid * 16, dE1 = tid * 16 + 8;       // shorts

  // ---- X staging geometry (async DMA, pre-swizzled source) ----
  const int xrow = tid >> 2;                          // 0..127
  const int xkc = (tid & 3) ^ ((xrow >> 1) & 3);
  const unsigned short* xP = xbf + (size_t)(bb * 128 + xrow) * DDIM + xkc * 8;
  const int dX = 8192 + tid * 8;                      // shorts, X block at +8192

  float e2a = 0.f;

  // ---- fragment read byte-offsets (BK=32, swizzle-matched) ----
  const int WE = (wid >> 1) * 64;    // exemplar base (0,64,128,192)
  const int WB = (wid & 1) * 64;     // batch base (0,64)
  int eoff[4], xoff[4];
  {
    const int ch = lane >> 4;        // 0..3
    #pragma unroll
    for (int f = 0; f < 4; ++f) {
      int er = WE + f * 16 + (lane & 15);
      eoff[f] = er * 64 + ((ch ^ ((er >> 1) & 3)) * 16);
      int xr = WB + f * 16 + (lane & 15);
      xoff[f] = 16384 + xr * 64 + ((ch ^ ((xr >> 1) & 3)) * 16);
    }
  }

  float4 sEa, sEb, sEc, sEd;

#define ISSUE(KT) do {                                                  \
    const float* p0 = eP0 + (KT) * 32;                                  \
    const float* p1 = eP1 + (KT) * 32;                                  \
    sEa = *(const float4*)p0; sEb = *(const float4*)(p0 + 4);           \
    sEc = *(const float4*)p1; sEd = *(const float4*)(p1 + 4);           \
  } while (0)

#define CVTSTORE(KT, BUFS) do {                                         \
    const float4 w0 = *(const float4*)&wlds[(KT) * 32 + kc0 * 8];       \
    const float4 w1 = *(const float4*)&wlds[(KT) * 32 + kc0 * 8 + 4];   \
    const float4 w2 = *(const float4*)&wlds[(KT) * 32 + kc1 * 8];       \
    const float4 w3 = *(const float4*)&wlds[(KT) * 32 + kc1 * 8 + 4];   \
    u32x4 pk;                                                           \
    pk[0] = cvtpk(sEa.x, sEa.y); pk[1] = cvtpk(sEa.z, sEa.w);           \
    pk[2] = cvtpk(sEb.x, sEb.y); pk[3] = cvtpk(sEb.z, sEb.w);           \
    e2a += sEa.x*sEa.x*w0.x + sEa.y*sEa.y*w0.y                          \
         + sEa.z*sEa.z*w0.z + sEa.w*sEa.w*w0.w                          \
         + sEb.x*sEb.x*w1.x + sEb.y*sEb.y*w1.y                          \
         + sEb.z*sEb.z*w1.z + sEb.w*sEb.w*w1.w;                         \
    *(u32x4*)&smem[(BUFS) + dE0] = pk;                                  \
    pk[0] = cvtpk(sEc.x, sEc.y); pk[1] = cvtpk(sEc.z, sEc.w);           \
    pk[2] = cvtpk(sEd.x, sEd.y); pk[3] = cvtpk(sEd.z, sEd.w);           \
    e2a += sEc.x*sEc.x*w2.x + sEc.y*sEc.y*w2.y                          \
         + sEc.z*sEc.z*w2.z + sEc.w*sEc.w*w2.w                          \
         + sEd.x*sEd.x*w3.x + sEd.y*sEd.y*w3.y                          \
         + sEd.z*sEd.z*w3.z + sEd.w*sEd.w*w3.w;                         \
    *(u32x4*)&smem[(BUFS) + dE1] = pk;                                  \
  } while (0)

  __syncthreads();   // wlds ready

  // prologue: stage K-tile 0 into buffer 0
  ISSUE(0);
  async16(xP, &smem[dX]);
  CVTSTORE(0, 0);
  __syncthreads();

  f32x4 acc[4][4] = {};
  for (int kt = 0; kt < 16; ++kt) {
    const int cur = kt & 1;
    const int nb = (cur ^ 1) * 12288;
    if (kt < 15) {
      ISSUE(kt + 1);                           // E f32 loads fly under MFMA
      async16(xP + (kt + 1) * 32, &smem[nb + dX]);  // X DMA into other buffer
    }
    const char* base = (const char*)smem + cur * 24576;
    bf16x8 ef[4], xf[4];
    #pragma unroll
    for (int f = 0; f < 4; ++f) {
      ef[f] = *(const bf16x8*)(base + eoff[f]);
      xf[f] = *(const bf16x8*)(base + xoff[f]);
    }
    #pragma unroll
    for (int fe = 0; fe < 4; ++fe)
      #pragma unroll
      for (int fb = 0; fb < 4; ++fb)
        acc[fe][fb] = __builtin_amdgcn_mfma_f32_16x16x32_bf16(ef[fe], xf[fb], acc[fe][fb], 0, 0, 0);
    if (kt < 15) CVTSTORE(kt + 1, nb);
    __syncthreads();   // reads of cur done; next-tile E writes + X DMA landed
  }
#undef ISSUE
#undef CVTSTORE

  // ---- finalize e2w: the 2 threads of each row ----
  e2a += __shfl_xor(e2a, 1, 64);
  if ((tid & 1) == 0) e2l[erow] = e2a;
  __syncthreads();

  // ---- epilogue: sim = exp(-beta*d); class-reduce via one-hot MFMA ----
  const float beta = softplus(bu[0]) + EPSF;
  const int rb = (lane >> 4) * 4;
  const int col = lane & 15;
  float e2v[4][4];
  #pragma unroll
  for (int fe = 0; fe < 4; ++fe)
    #pragma unroll
    for (int r = 0; r < 4; ++r)
      e2v[fe][r] = e2l[WE + fe * 16 + rb + r];
  half4 oh[4];
  #pragma unroll
  for (int fe = 0; fe < 4; ++fe)
    #pragma unroll
    for (int i = 0; i < 4; ++i)
      oh[fe][i] = (lab[WE + fe * 16 + rb + i] == col) ? (_Float16)1.0f : (_Float16)0.0f;

  f32x4 csv[4];
  #pragma unroll
  for (int fb = 0; fb < 4; ++fb) {
    const float xv = x2w[bb * 128 + WB + fb * 16 + col];
    f32x4 cs = {0.f, 0.f, 0.f, 0.f};
    #pragma unroll
    for (int fe = 0; fe < 4; ++fe) {
      half4 sa;
      #pragma unroll
      for (int r = 0; r < 4; ++r)
        sa[r] = (_Float16)__expf(-beta * (xv + e2v[fe][r] - 2.0f * acc[fe][fb][r]));
      cs = __builtin_amdgcn_mfma_f32_16x16x16f16(sa, oh[fe], cs, 0, 0, 0);
    }
    csv[fb] = cs;   // cs[r]: class-sum for batch row (WB+fb*16+rb+r), class=col
  }

  // intra-block combine of the 4 exemplar quarters via LDS (reuse smem, 32KB):
  // red[quad][brow_local 128][16], quad = WE>>6.
  float* red = (float*)smem;
  const int quad = WE >> 6;
  #pragma unroll
  for (int fb = 0; fb < 4; ++fb)
    #pragma unroll
    for (int r = 0; r < 4; ++r)
      red[((quad * 128 + (WB + fb * 16 + rb + r)) << 4) | col] = csv[fb][r];
  __syncthreads();

  // sum quarters, store block partial (128 x 16 f32) coalesced (float4/thread)
  {
    const int o = tid * 4;        // 0..2047
    const int rl = o >> 4;        // brow_local 0..127
    const int c0b = o & 12;       // 0,4,8,12
    float4 v0 = *(const float4*)&red[(rl << 4) | c0b];
    float4 v1 = *(const float4*)&red[((128 + rl) << 4) | c0b];
    float4 v2 = *(const float4*)&red[((256 + rl) << 4) | c0b];
    float4 v3 = *(const float4*)&red[((384 + rl) << 4) | c0b];
    float4 r0 = {v0.x + v1.x + v2.x + v3.x, v0.y + v1.y + v2.y + v3.y,
                 v0.z + v1.z + v2.z + v3.z, v0.w + v1.w + v2.w + v3.w};
    *(float4*)&part[(((size_t)(bb * 128 + rl)) * NECH + be) * NCP + c0b] = r0;
  }
}

// ---- kernel 3: logits = gamma * log( sum_ne part[b][ne][c] + eps ) ----------
__global__ __launch_bounds__(256) void reduce_logits(
    const float* __restrict__ part, const float* __restrict__ gu,
    float* __restrict__ out) {
  const int lane = threadIdx.x & 63, wd = threadIdx.x >> 6;
  const int b = blockIdx.x * 4 + wd;
  const int cl = lane & 15, ch0 = lane >> 4;
  const float* p = part + (size_t)b * NECH * NCP;
  float v = 0.f;
  #pragma unroll
  for (int k = 0; k < 16; ++k)
    v += p[(ch0 + 4 * k) * NCP + cl];
  v += __shfl_xor(v, 16, 64);
  v += __shfl_xor(v, 32, 64);
  if (lane < NC) {
    const float gamma = softplus(gu[0]) + EPSF;
    out[b * NC + lane] = gamma * logf(v + EPSF);
  }
}

extern "C" void kernel_launch(void* const* d_in, const int* in_sizes, int n_in,
                              void* d_out, int out_size, void* d_ws, size_t ws_size,
                              hipStream_t stream) {
  const float* x  = (const float*)d_in[0];
  const float* ex = (const float*)d_in[1];
  const int* labels = (const int*)d_in[2];
  const float* wu = (const float*)d_in[3];
  const float* gu = (const float*)d_in[4];
  const float* bu = (const float*)d_in[5];
  float* out = (float*)d_out;
  const int B = in_sizes[0] / DDIM;   // 1024
  const int N = in_sizes[2];          // 16384

  char* ws = (char*)d_ws;
  const size_t off_w    = 0;
  const size_t off_x2w  = 4096;
  const size_t off_xbf  = off_x2w + (size_t)B * 4;
  const size_t off_part = off_xbf + (size_t)B * DDIM * 2;
  const size_t need     = off_part + (size_t)B * NECH * NCP * 4;
  if (ws_size < need) return;   // insufficient scratch; fail loudly (zeros)

  float* wbuf = (float*)(ws + off_w);
  float* x2w  = (float*)(ws + off_x2w);
  unsigned short* xbf = (unsigned short*)(ws + off_xbf);
  float* part = (float*)(ws + off_part);

  prep_x<<<B / 8, 512, 0, stream>>>(x, wu, wbuf, xbf, x2w);
  gemm_mega<<<(N / 256) * (B / 128), 512, 0, stream>>>(ex, xbf, labels, wbuf, x2w, bu, part);
  reduce_logits<<<B / 4, 256, 0, stream>>>(part, gu, out);
}